// Round 1
// baseline (454.905 us; speedup 1.0000x reference)
//
#include <hip/hip_runtime.h>
#include <stdint.h>

#define M_DIM 8192
#define K_DIM 4096
#define N_DIM 4096
#define FP8_MAX 448.0f
#define KT (K_DIM / 64)   // 64 k-tiles of depth 64

typedef float floatx16 __attribute__((ext_vector_type(16)));
typedef int intx8 __attribute__((ext_vector_type(8)));

// Tiled fp8 layout (unchanged from proven v2, for 32x32x64 scaled MFMA):
//   tensor -> [128-row x 64-k] tiles of 8192 B; tile (i=row/128, b=k/64) at
//   (i*(K/64)+b)*8192.
//   Within a tile: row = mi*32 + r5, k = h*32 + kq*16 + j
//     offset = kq*4096 + mi*1024 + (h*32 + r5)*16
//   MFMA 32x32x64 fragment: lane l holds row r5=l&31, k-half h=l>>5, 32
//   consecutive k bytes -> fragment read = TWO ds_read_b128 at
//   (kq*4096 + mi*1024) + 16*lane  (lane-contiguous, conflict-free; T2 moot).
//
// GEMM v3: 256x256 tile, 8 waves (2Mx4N), 3-slot circular LDS (96 KB),
// prefetch distance 2 with counted vmcnt(4) at iteration boundaries (T4 -
// loads stay in flight across barriers), 2 phases/K-tile each with
// {ds_read || stage-issue -> barrier -> setprio(1) MFMA x4 setprio(0) ->
// barrier} (T3), per the verified 8-phase template structure.

// ---------- helpers ----------

__device__ __forceinline__ uint32_t pack4_fp8(float a, float b, float c, float d) {
    int v = __builtin_amdgcn_cvt_pk_fp8_f32(a, b, 0, false);
    v = __builtin_amdgcn_cvt_pk_fp8_f32(c, d, v, true);
    return (uint32_t)v;
}

__device__ __forceinline__ void gload_lds16(const uint8_t* g, uint8_t* l) {
    __builtin_amdgcn_global_load_lds(
        (const __attribute__((address_space(1))) uint32_t*)g,
        (__attribute__((address_space(3))) uint32_t*)l,
        16, 0, 0);
}

__device__ __forceinline__ float scale_from_amax(float amax) {
    return FP8_MAX / fmaxf(amax, 1e-12f);
}

// ---------- kernel 0: init amax slots ----------

__global__ void init_amax_kernel(uint32_t* amax) {
    amax[0] = 0u;
    amax[1] = 0u;
}

// ---------- kernel 1: fused per-tensor amax (x and w in one launch) ----------

__global__ __launch_bounds__(256)
void amax_kernel(const float* __restrict__ x, const float* __restrict__ w,
                 uint32_t* __restrict__ out_bits) {
    bool isX = blockIdx.x < 2048;
    const float* src = isX ? x : w;
    long n4 = (isX ? (long)M_DIM * K_DIM : (long)K_DIM * N_DIM) >> 2;
    int bid = isX ? blockIdx.x : blockIdx.x - 2048;
    int nb = isX ? 2048 : 1024;
    long i = (long)bid * blockDim.x + threadIdx.x;
    long stride = (long)nb * blockDim.x;
    const float4* s4 = (const float4*)src;
    float m = 0.0f;
    for (long j = i; j < n4; j += stride) {
        float4 v = s4[j];
        m = fmaxf(m, fmaxf(fmaxf(fabsf(v.x), fabsf(v.y)), fmaxf(fabsf(v.z), fabsf(v.w))));
    }
    #pragma unroll
    for (int off = 32; off > 0; off >>= 1)
        m = fmaxf(m, __shfl_down(m, off, 64));
    __shared__ float smax[4];
    int wave = threadIdx.x >> 6;
    if ((threadIdx.x & 63) == 0) smax[wave] = m;
    __syncthreads();
    if (threadIdx.x == 0) {
        float bm = fmaxf(fmaxf(smax[0], smax[1]), fmaxf(smax[2], smax[3]));
        atomicMax(out_bits + (isX ? 0 : 1), __float_as_uint(bm));
    }
}

// ---------- kernel 2: fused quantize x and w -> tiled fp8 layouts ----------
// blocks [0,4096): x tiles (M/128=64 x K/64=64); [4096,6144): wT tiles (N/128=32 x K/64=64)

__global__ __launch_bounds__(256)
void quant_kernel(const float* __restrict__ x, const float* __restrict__ w,
                  uint8_t* __restrict__ qx, uint8_t* __restrict__ qwT,
                  const uint32_t* __restrict__ amax_bits) {
    int b = blockIdx.x;
    if (b < 4096) {
        float scale = scale_from_amax(__uint_as_float(amax_bits[0]));
        int iy = b >> 6, ib = b & 63;
        const float* src = x + (long)iy * 128 * K_DIM;
        uint8_t* outT = qx + (size_t)b * 8192;
        int kb = ib * 64;
        #pragma unroll
        for (int it = 0; it < 2; ++it) {
            int G = threadIdx.x + it * 256;
            int kq = G >> 8, rem = G & 255;
            int mi = rem >> 6, h = (rem >> 5) & 1, r5 = rem & 31;
            const float4* p = (const float4*)(src + (long)(mi * 32 + r5) * K_DIM
                                              + kb + h * 32 + kq * 16);
            float4 v0 = p[0], v1 = p[1], v2 = p[2], v3 = p[3];
            uint4 o;
            o.x = pack4_fp8(v0.x * scale, v0.y * scale, v0.z * scale, v0.w * scale);
            o.y = pack4_fp8(v1.x * scale, v1.y * scale, v1.z * scale, v1.w * scale);
            o.z = pack4_fp8(v2.x * scale, v2.y * scale, v2.z * scale, v2.w * scale);
            o.w = pack4_fp8(v3.x * scale, v3.y * scale, v3.z * scale, v3.w * scale);
            *(uint4*)(outT + (size_t)G * 16) = o;   // consecutive G -> coalesced
        }
    } else {
        float scale = scale_from_amax(__uint_as_float(amax_bits[1]));
        b -= 4096;
        int iy = b >> 6, ib = b & 63;     // iy = n-tile
        int n0 = iy * 128, kb = ib * 64;
        uint8_t* outT = qwT + (size_t)b * 8192;
        #pragma unroll
        for (int it = 0; it < 2; ++it) {
            int G = threadIdx.x + it * 256;
            int kq = G >> 8, rem = G & 255;
            int mi = rem >> 6, h = (rem >> 5) & 1, r5 = rem & 31;
            int n = n0 + mi * 32 + r5;
            const float* col = w + (long)(kb + h * 32 + kq * 16) * N_DIM + n;
            float v[16];
            #pragma unroll
            for (int j = 0; j < 16; ++j)
                v[j] = col[(long)j * N_DIM] * scale;   // wave-coalesced per j
            uint4 o;
            o.x = pack4_fp8(v[0], v[1], v[2], v[3]);
            o.y = pack4_fp8(v[4], v[5], v[6], v[7]);
            o.z = pack4_fp8(v[8], v[9], v[10], v[11]);
            o.w = pack4_fp8(v[12], v[13], v[14], v[15]);
            *(uint4*)(outT + (size_t)G * 16) = o;
        }
    }
}

// ---------- kernel 3: MX-scaled fp8 MFMA GEMM, 256x256 pipelined ----------

#define UNIT_SCALE 0x7F7F7F7F   // e8m0 0x7F = 2^0 = 1.0 per 32-elem block

union Frag { intx8 v; int4 q[2]; };

#define MFMA_SC(A, B, Cacc) \
    __builtin_amdgcn_mfma_scale_f32_32x32x64_f8f6f4( \
        (A).v, (B).v, (Cacc), 0, 0, 0, UNIT_SCALE, 0, UNIT_SCALE)

__global__ __launch_bounds__(512, 2)
void gemm_kernel(const uint8_t* __restrict__ qx, const uint8_t* __restrict__ qwT,
                 const float* __restrict__ bias, float* __restrict__ C,
                 const uint32_t* __restrict__ amax_bits) {
    float sx = scale_from_amax(__uint_as_float(amax_bits[0]));
    float sw = scale_from_amax(__uint_as_float(amax_bits[1]));
    float dq = 1.0f / (sx * sw);

    // 3 slots x (A: 2x8KB chunks, B: 2x8KB chunks) = 96 KB
    __shared__ __align__(16) uint8_t lds[3 * 32768];

    int tid = threadIdx.x;
    int wave = tid >> 6;
    int lane = tid & 63;
    int wm = wave >> 2;        // 0..1 : 128 rows each
    int wn = wave & 3;         // 0..3 : 64 cols each
    int i0 = blockIdx.y * 2;   // first 128-row A tile index
    int j0 = blockIdx.x * 2;   // first 128-col B tile index

    const uint8_t* aSrc0 = qx  + ((size_t)(i0 + 0) * KT) * 8192 + tid * 16;
    const uint8_t* aSrc1 = qx  + ((size_t)(i0 + 1) * KT) * 8192 + tid * 16;
    const uint8_t* bSrc0 = qwT + ((size_t)(j0 + 0) * KT) * 8192 + tid * 16;
    const uint8_t* bSrc1 = qwT + ((size_t)(j0 + 1) * KT) * 8192 + tid * 16;

    // prologue: stage tile 0 -> slot0, tile 1 -> slot1 (8 gloads/thread)
    #pragma unroll
    for (int tt = 0; tt < 2; ++tt) {
        uint8_t* sl = lds + tt * 32768;
        size_t off = (size_t)tt * 8192;
        gload_lds16(aSrc0 + off, sl + tid * 16);
        gload_lds16(aSrc1 + off, sl + 8192 + tid * 16);
        gload_lds16(bSrc0 + off, sl + 16384 + tid * 16);
        gload_lds16(bSrc1 + off, sl + 24576 + tid * 16);
    }
    asm volatile("s_waitcnt vmcnt(4)" ::: "memory");  // tile 0 landed; tile 1 in flight
    __builtin_amdgcn_s_barrier();

    floatx16 acc[4][2];
    #pragma unroll
    for (int i = 0; i < 4; ++i)
        #pragma unroll
        for (int j = 0; j < 2; ++j)
            acc[i][j] = (floatx16)0.0f;

    int l16 = lane * 16;
    int s = 0;
    for (int t = 0; t < KT; ++t) {
        const uint8_t* slot = lds + s * 32768;
        const uint8_t* aB = slot + wm * 8192;                                // wave's A chunk
        const uint8_t* bB = slot + 16384 + (wn >> 1) * 8192 + (wn & 1) * 2048; // wave's B half-chunk
        int ns = s + 2; if (ns >= 3) ns -= 3;
        uint8_t* psl = lds + ns * 32768;          // prefetch slot for tile t+2
        bool pf = (t + 2 < KT);
        size_t poff = (size_t)(t + 2) * 8192;

        // ---- phase 0: frags for mi 0,1 + both B frags; issue A prefetch ----
        Frag fa0, fa1, fb0, fb1;
        fa0.q[0] = *(const int4*)(aB + l16);
        fa0.q[1] = *(const int4*)(aB + 4096 + l16);
        fa1.q[0] = *(const int4*)(aB + 1024 + l16);
        fa1.q[1] = *(const int4*)(aB + 5120 + l16);
        fb0.q[0] = *(const int4*)(bB + l16);
        fb0.q[1] = *(const int4*)(bB + 4096 + l16);
        fb1.q[0] = *(const int4*)(bB + 1024 + l16);
        fb1.q[1] = *(const int4*)(bB + 5120 + l16);
        if (pf) {
            gload_lds16(aSrc0 + poff, psl + tid * 16);
            gload_lds16(aSrc1 + poff, psl + 8192 + tid * 16);
        }
        __builtin_amdgcn_s_barrier();
        __builtin_amdgcn_s_setprio(1);
        acc[0][0] = MFMA_SC(fa0, fb0, acc[0][0]);
        acc[0][1] = MFMA_SC(fa0, fb1, acc[0][1]);
        acc[1][0] = MFMA_SC(fa1, fb0, acc[1][0]);
        acc[1][1] = MFMA_SC(fa1, fb1, acc[1][1]);
        __builtin_amdgcn_s_setprio(0);
        __builtin_amdgcn_s_barrier();

        // ---- phase 1: frags for mi 2,3; issue B prefetch ----
        Frag fa2, fa3;
        fa2.q[0] = *(const int4*)(aB + 2048 + l16);
        fa2.q[1] = *(const int4*)(aB + 6144 + l16);
        fa3.q[0] = *(const int4*)(aB + 3072 + l16);
        fa3.q[1] = *(const int4*)(aB + 7168 + l16);
        if (pf) {
            gload_lds16(bSrc0 + poff, psl + 16384 + tid * 16);
            gload_lds16(bSrc1 + poff, psl + 24576 + tid * 16);
        }
        __builtin_amdgcn_s_barrier();
        __builtin_amdgcn_s_setprio(1);
        acc[2][0] = MFMA_SC(fa2, fb0, acc[2][0]);
        acc[2][1] = MFMA_SC(fa2, fb1, acc[2][1]);
        acc[3][0] = MFMA_SC(fa3, fb0, acc[3][0]);
        acc[3][1] = MFMA_SC(fa3, fb1, acc[3][1]);
        __builtin_amdgcn_s_setprio(0);

        // counted drain: need tile t+1 resident for next iter; keep t+2 in flight
        if (t < KT - 2) {
            asm volatile("s_waitcnt vmcnt(4)" ::: "memory");
        } else if (t == KT - 2) {
            asm volatile("s_waitcnt vmcnt(0)" ::: "memory");
        }
        __builtin_amdgcn_s_barrier();
        s = (s == 2) ? 0 : s + 1;
    }

    // epilogue: 32x32 C/D layout: col = lane&31, row = (reg&3) + 8*(reg>>2) + 4*(lane>>5)
    int cn = lane & 31;
    int h4 = (lane >> 5) * 4;
    long tileM = (long)blockIdx.y * 256;
    long tileN = (long)blockIdx.x * 256;
    #pragma unroll
    for (int ni = 0; ni < 2; ++ni) {
        long col = tileN + wn * 64 + ni * 32 + cn;
        float bv = bias[col];
        #pragma unroll
        for (int mi = 0; mi < 4; ++mi) {
            long rowBase = tileM + wm * 128 + mi * 32 + h4;
            floatx16 a = acc[mi][ni];
            #pragma unroll
            for (int rg = 0; rg < 4; ++rg) {
                long row = rowBase + 8 * rg;
                #pragma unroll
                for (int rr = 0; rr < 4; ++rr)
                    C[(row + rr) * N_DIM + col] = a[rg * 4 + rr] * dq + bv;
            }
        }
    }
}

// ---------- launch ----------

extern "C" void kernel_launch(void* const* d_in, const int* in_sizes, int n_in,
                              void* d_out, int out_size, void* d_ws, size_t ws_size,
                              hipStream_t stream) {
    const float* x = (const float*)d_in[0];     // [M][K]
    const float* w = (const float*)d_in[1];     // [K][N]
    const float* bias = (const float*)d_in[2];  // [N]
    float* out = (float*)d_out;                 // [M][N]

    uint32_t* amax = (uint32_t*)d_ws;           // [0]=amax_x, [1]=amax_w
    uint8_t* qx = (uint8_t*)d_ws + 256;
    uint8_t* qwT = qx + (size_t)M_DIM * K_DIM;

    init_amax_kernel<<<1, 64, 0, stream>>>(amax);
    amax_kernel<<<3072, 256, 0, stream>>>(x, w, amax);
    quant_kernel<<<6144, 256, 0, stream>>>(x, w, qx, qwT, amax);
    gemm_kernel<<<dim3(N_DIM / 256, M_DIM / 256), 512, 0, stream>>>(qx, qwT, bias, out, amax);
}